// Round 1
// baseline (227.797 us; speedup 1.0000x reference)
//
#include <hip/hip_runtime.h>

#define BB 4096   // batch
#define TT 512    // time steps
#define DD 32     // input dim
#define NL 10     // layers
#define CPW 6     // chains per wave (10 lanes each, lanes 60..63 idle)

static constexpr float L2E = 1.4426950408889634f;   // log2(e)

__device__ __forceinline__ float fexp2(float x) { return __builtin_amdgcn_exp2f(x); }
__device__ __forceinline__ float frcp(float x)  { return __builtin_amdgcn_rcpf(x); }

// ---------------------------------------------------------------------------
// Kernel A: G0[t][b][k] = scale[k] * (W_ih0[k,:] . x[b,t,:] + b0[k])
// scale = {-L2E, -L2E, -2*L2E, -L2E}  (folds sigmoid/tanh exp2 conversion)
// Reads x coalesced (wave reads 8KB contiguous); 16B-scattered writes are
// absorbed by L2/L3 (G0 = 32 MiB, consumed immediately by kernel B).
// ---------------------------------------------------------------------------
__global__ __launch_bounds__(256) void k_transform(
    const float* __restrict__ x, const float* __restrict__ Wih0,
    const float* __restrict__ b0, float* __restrict__ G0)
{
    __shared__ float w[132];
    int tid = threadIdx.x;
    if (tid < 128) w[tid] = Wih0[tid];
    if (tid < 4)   w[128 + tid] = b0[tid];
    __syncthreads();

    int n = blockIdx.x * 256 + tid;     // n = b*TT + t
    int b = n >> 9;
    int t = n & (TT - 1);

    const float4* xp = (const float4*)(x + (size_t)n * DD);
    float a0 = w[128], a1 = w[129], a2 = w[130], a3 = w[131];
#pragma unroll
    for (int ch = 0; ch < 8; ch++) {
        float4 xv = xp[ch];
        const float* w0 = &w[0 * 32 + ch * 4];
        const float* w1 = &w[1 * 32 + ch * 4];
        const float* w2 = &w[2 * 32 + ch * 4];
        const float* w3 = &w[3 * 32 + ch * 4];
        a0 += xv.x * w0[0] + xv.y * w0[1] + xv.z * w0[2] + xv.w * w0[3];
        a1 += xv.x * w1[0] + xv.y * w1[1] + xv.z * w1[2] + xv.w * w1[3];
        a2 += xv.x * w2[0] + xv.y * w2[1] + xv.z * w2[2] + xv.w * w2[3];
        a3 += xv.x * w3[0] + xv.y * w3[1] + xv.z * w3[2] + xv.w * w3[3];
    }
    float4 o;
    o.x = -L2E * a0;
    o.y = -L2E * a1;
    o.z = -2.f * L2E * a2;
    o.w = -L2E * a3;
    ((float4*)G0)[(size_t)t * BB + b] = o;
}

// ---------------------------------------------------------------------------
// Kernel B: skewed wave-internal pipeline.
// lane = c*10 + l  (c = chain-in-wave, l = layer). Step s: lane l processes
// timestep t = s - l. Handoff h_{l-1}(t) comes from lane-1's previous step via
// __shfl_up. G0 prefetched 8 steps deep (static-indexed ring, unroll-8).
// ---------------------------------------------------------------------------
__global__ __launch_bounds__(64) void k_pipe(
    const float* __restrict__ G0, const float* __restrict__ Whh0,
    const float* __restrict__ Wihr, const float* __restrict__ Whhr,
    const float* __restrict__ br, float* __restrict__ out)
{
    int lane = threadIdx.x;
    int cidx = lane / NL;
    int l = lane - cidx * NL;
    if (cidx >= CPW) return;                 // 4 idle lanes, never sourced
    int chain = blockIdx.x * CPW + cidx;
    bool vc = (chain < BB);

    const float sk0 = -L2E, sk1 = -L2E, sk2 = -2.f * L2E, sk3 = -L2E;
    float wi0 = 0, wi1 = 0, wi2 = 0, wi3 = 0;
    float wh0, wh1, wh2, wh3;
    float bb0 = 0, bb1 = 0, bb2 = 0, bb3 = 0;
    if (l == 0) {
        wh0 = sk0 * Whh0[0]; wh1 = sk1 * Whh0[1];
        wh2 = sk2 * Whh0[2]; wh3 = sk3 * Whh0[3];
    } else {
        const float* pi = Wihr + (l - 1) * 4;
        const float* ph = Whhr + (l - 1) * 4;
        const float* pb = br   + (l - 1) * 4;
        wi0 = sk0 * pi[0]; wi1 = sk1 * pi[1]; wi2 = sk2 * pi[2]; wi3 = sk3 * pi[3];
        wh0 = sk0 * ph[0]; wh1 = sk1 * ph[1]; wh2 = sk2 * ph[2]; wh3 = sk3 * ph[3];
        bb0 = sk0 * pb[0]; bb1 = sk1 * pb[1]; bb2 = sk2 * pb[2]; bb3 = sk3 * pb[3];
    }

    float h = 0.f, cs = 0.f, hout = 0.f;
    float4 buf[8];
#pragma unroll
    for (int i = 0; i < 8; i++) buf[i] = make_float4(0.f, 0.f, 0.f, 0.f);
    bool isl0 = (l == 0), isl9 = (l == NL - 1);
    if (isl0 && vc) {
#pragma unroll
        for (int i = 0; i < 8; i++)
            buf[i] = ((const float4*)G0)[(size_t)i * BB + chain];
    }

    for (int sb = 0; sb < 528; sb += 8) {      // 521 live steps, padded to 528
#pragma unroll
        for (int j = 0; j < 8; j++) {
            int s = sb + j;
            int t = s - l;
            bool active = vc && (t >= 0) && (t < TT);

            float hin = __shfl_up(hout, 1);    // h_{l-1}(t), produced last step
            float4 g0 = buf[j];
            if (isl0 && vc && (s + 8) < TT)    // refill ring slot (static idx)
                buf[j] = ((const float4*)G0)[(size_t)(s + 8) * BB + chain];

            float p0 = isl0 ? g0.x : fmaf(hin, wi0, bb0);
            float p1 = isl0 ? g0.y : fmaf(hin, wi1, bb1);
            float p2 = isl0 ? g0.z : fmaf(hin, wi2, bb2);
            float p3 = isl0 ? g0.w : fmaf(hin, wi3, bb3);
            float u0 = fmaf(h, wh0, p0);       // u = -L2E*g (gate pre-acts, scaled)
            float u1 = fmaf(h, wh1, p1);
            float u2 = fmaf(h, wh2, p2);
            float u3 = fmaf(h, wh3, p3);

            float ig = frcp(1.f + fexp2(u0));                  // sigmoid(g0)
            float fg = frcp(1.f + fexp2(u1));                  // sigmoid(g1)
            float gg = fmaf(2.f, frcp(1.f + fexp2(u2)), -1.f); // tanh(g2)
            float og = frcp(1.f + fexp2(u3));                  // sigmoid(g3)
            float cn = fmaf(fg, cs, ig * gg);
            float th = fmaf(2.f, frcp(1.f + fexp2(-2.f * L2E * cn)), -1.f); // tanh(c)
            float hn = og * th;

            if (active) { cs = cn; h = hn; hout = hn; }
            if (isl9 && active)
                out[(size_t)chain * TT + t] = 60.f * frcp(1.f + fexp2(-L2E * hn));
        }
    }
}

// ---------------------------------------------------------------------------
// Fallback (ws too small): one thread per chain, monolithic.
// ---------------------------------------------------------------------------
__device__ __forceinline__ void cell_up(float u0, float u1, float u2, float u3,
                                        float& h, float& c)
{
    float ig = frcp(1.f + fexp2(u0));
    float fg = frcp(1.f + fexp2(u1));
    float gg = fmaf(2.f, frcp(1.f + fexp2(u2)), -1.f);
    float og = frcp(1.f + fexp2(u3));
    float cn = fmaf(fg, c, ig * gg);
    float th = fmaf(2.f, frcp(1.f + fexp2(-2.f * L2E * cn)), -1.f);
    c = cn; h = og * th;
}

__global__ __launch_bounds__(256) void k_mono(
    const float* __restrict__ x, const float* __restrict__ Wih0,
    const float* __restrict__ Whh0, const float* __restrict__ b0,
    const float* __restrict__ Wihr, const float* __restrict__ Whhr,
    const float* __restrict__ br, float* __restrict__ out)
{
    __shared__ float w[132];
    int tid = threadIdx.x;
    if (tid < 128) {
        int g = tid >> 5;
        w[tid] = ((g == 2) ? (-2.f * L2E) : (-L2E)) * Wih0[tid];
    }
    if (tid < 4) w[128 + tid] = ((tid == 2) ? (-2.f * L2E) : (-L2E)) * b0[tid];
    __syncthreads();

    int b = blockIdx.x * 256 + tid;
    float wh0[4], wir[NL - 1][4], whr[NL - 1][4], brr[NL - 1][4];
#pragma unroll
    for (int k = 0; k < 4; k++)
        wh0[k] = ((k == 2) ? (-2.f * L2E) : (-L2E)) * Whh0[k];
#pragma unroll
    for (int ll = 0; ll < NL - 1; ll++)
#pragma unroll
        for (int k = 0; k < 4; k++) {
            float s = (k == 2) ? (-2.f * L2E) : (-L2E);
            wir[ll][k] = s * Wihr[ll * 4 + k];
            whr[ll][k] = s * Whhr[ll * 4 + k];
            brr[ll][k] = s * br[ll * 4 + k];
        }
    float hh[NL], cc[NL];
#pragma unroll
    for (int ll = 0; ll < NL; ll++) { hh[ll] = 0.f; cc[ll] = 0.f; }

    const float4* xb = (const float4*)(x + (size_t)b * TT * DD);
    for (int t = 0; t < TT; t++) {
        float a0 = w[128], a1 = w[129], a2 = w[130], a3 = w[131];
#pragma unroll
        for (int ch = 0; ch < 8; ch++) {
            float4 xv = xb[t * 8 + ch];
            a0 += xv.x * w[0 * 32 + ch * 4] + xv.y * w[0 * 32 + ch * 4 + 1] + xv.z * w[0 * 32 + ch * 4 + 2] + xv.w * w[0 * 32 + ch * 4 + 3];
            a1 += xv.x * w[1 * 32 + ch * 4] + xv.y * w[1 * 32 + ch * 4 + 1] + xv.z * w[1 * 32 + ch * 4 + 2] + xv.w * w[1 * 32 + ch * 4 + 3];
            a2 += xv.x * w[2 * 32 + ch * 4] + xv.y * w[2 * 32 + ch * 4 + 1] + xv.z * w[2 * 32 + ch * 4 + 2] + xv.w * w[2 * 32 + ch * 4 + 3];
            a3 += xv.x * w[3 * 32 + ch * 4] + xv.y * w[3 * 32 + ch * 4 + 1] + xv.z * w[3 * 32 + ch * 4 + 2] + xv.w * w[3 * 32 + ch * 4 + 3];
        }
        float u0 = fmaf(hh[0], wh0[0], a0);
        float u1 = fmaf(hh[0], wh0[1], a1);
        float u2 = fmaf(hh[0], wh0[2], a2);
        float u3 = fmaf(hh[0], wh0[3], a3);
        cell_up(u0, u1, u2, u3, hh[0], cc[0]);
        float hin = hh[0];
#pragma unroll
        for (int ll = 1; ll < NL; ll++) {
            float v0 = fmaf(hin, wir[ll - 1][0], fmaf(hh[ll], whr[ll - 1][0], brr[ll - 1][0]));
            float v1 = fmaf(hin, wir[ll - 1][1], fmaf(hh[ll], whr[ll - 1][1], brr[ll - 1][1]));
            float v2 = fmaf(hin, wir[ll - 1][2], fmaf(hh[ll], whr[ll - 1][2], brr[ll - 1][2]));
            float v3 = fmaf(hin, wir[ll - 1][3], fmaf(hh[ll], whr[ll - 1][3], brr[ll - 1][3]));
            cell_up(v0, v1, v2, v3, hh[ll], cc[ll]);
            hin = hh[ll];
        }
        out[(size_t)b * TT + t] = 60.f * frcp(1.f + fexp2(-L2E * hh[NL - 1]));
    }
}

extern "C" void kernel_launch(void* const* d_in, const int* in_sizes, int n_in,
                              void* d_out, int out_size, void* d_ws, size_t ws_size,
                              hipStream_t stream)
{
    const float* x    = (const float*)d_in[0];
    const float* Wih0 = (const float*)d_in[1];
    const float* Whh0 = (const float*)d_in[2];
    const float* b0   = (const float*)d_in[3];
    const float* Wihr = (const float*)d_in[4];
    const float* Whhr = (const float*)d_in[5];
    const float* br   = (const float*)d_in[6];
    float* out = (float*)d_out;

    const size_t g0_bytes = (size_t)TT * BB * 4 * sizeof(float);   // 32 MiB
    if (ws_size >= g0_bytes) {
        float* G0 = (float*)d_ws;
        k_transform<<<(BB * TT) / 256, 256, 0, stream>>>(x, Wih0, b0, G0);
        int nblk = (BB + CPW - 1) / CPW;   // 683
        k_pipe<<<nblk, 64, 0, stream>>>(G0, Whh0, Wihr, Whhr, br, out);
    } else {
        k_mono<<<BB / 256, 256, 0, stream>>>(x, Wih0, Whh0, b0, Wihr, Whhr, br, out);
    }
}

// Round 2
// 191.243 us; speedup vs baseline: 1.1911x; 1.1911x over previous
//
#include <hip/hip_runtime.h>

#define BB 4096   // batch
#define TT 512    // time steps
#define DD 32     // input dim
#define NL 10     // layers
#define DEPTH 16  // G0 prefetch ring depth (steps)

static constexpr float L2E = 1.4426950408889634f;   // log2(e)

__device__ __forceinline__ float fexp2(float x) { return __builtin_amdgcn_exp2f(x); }
__device__ __forceinline__ float frcp(float x)  { return __builtin_amdgcn_rcpf(x); }

// row_shr:1 within each 16-lane row; lane 0 of a row gets 0 (bound_ctrl).
__device__ __forceinline__ float dpp_shr1(float x) {
    int r = __builtin_amdgcn_update_dpp(0, __float_as_int(x), 0x111, 0xF, 0xF, true);
    return __int_as_float(r);
}

// ---------------------------------------------------------------------------
// Kernel A: G0[b][t][k] = scale[k] * (W_ih0[k,:] . x[b,t,:] + b0[k])
// scale = {-L2E, -L2E, -2*L2E, -L2E}. Coalesced float4 writes ([b][t] layout).
// ---------------------------------------------------------------------------
__global__ __launch_bounds__(256) void k_transform(
    const float* __restrict__ x, const float* __restrict__ Wih0,
    const float* __restrict__ b0, float* __restrict__ G0)
{
    __shared__ float w[132];
    int tid = threadIdx.x;
    if (tid < 128) w[tid] = Wih0[tid];
    if (tid < 4)   w[128 + tid] = b0[tid];
    __syncthreads();

    int n = blockIdx.x * 256 + tid;     // n = b*TT + t

    const float4* xp = (const float4*)(x + (size_t)n * DD);
    float a0 = w[128], a1 = w[129], a2 = w[130], a3 = w[131];
#pragma unroll
    for (int ch = 0; ch < 8; ch++) {
        float4 xv = xp[ch];
        const float* w0 = &w[0 * 32 + ch * 4];
        const float* w1 = &w[1 * 32 + ch * 4];
        const float* w2 = &w[2 * 32 + ch * 4];
        const float* w3 = &w[3 * 32 + ch * 4];
        a0 += xv.x * w0[0] + xv.y * w0[1] + xv.z * w0[2] + xv.w * w0[3];
        a1 += xv.x * w1[0] + xv.y * w1[1] + xv.z * w1[2] + xv.w * w1[3];
        a2 += xv.x * w2[0] + xv.y * w2[1] + xv.z * w2[2] + xv.w * w2[3];
        a3 += xv.x * w3[0] + xv.y * w3[1] + xv.z * w3[2] + xv.w * w3[3];
    }
    float4 o;
    o.x = -L2E * a0;
    o.y = -L2E * a1;
    o.z = -2.f * L2E * a2;
    o.w = -L2E * a3;
    ((float4*)G0)[n] = o;               // coalesced: consecutive tid -> consecutive 16B
}

// ---------------------------------------------------------------------------
// Kernel B: skewed pipeline, one chain per 16-lane row (4 chains/wave).
// lane&15 = layer l (0..9 live, 10..15 junk); handoff h_{l-1}(t) via DPP
// row_shr:1 (lane-1's h from the previous step). Cell state kept pre-scaled:
// cs = -2*L2E*c, folding the tanh-argument scale out of the critical path.
// 1024 blocks x 1 wave = 1 wave per SIMD machine-wide.
// ---------------------------------------------------------------------------
__global__ __launch_bounds__(64) void k_pipe(
    const float* __restrict__ G0, const float* __restrict__ Whh0,
    const float* __restrict__ Wihr, const float* __restrict__ Whhr,
    const float* __restrict__ br, float* __restrict__ out)
{
    int lane = threadIdx.x & 63;
    int cidx = lane >> 4;
    int l = lane & 15;                     // 0..9 live
    int chain = blockIdx.x * 4 + cidx;     // < 4096 always

    const float sk0 = -L2E, sk1 = -L2E, sk2 = -2.f * L2E, sk3 = -L2E;
    bool isl0 = (l == 0), isl9 = (l == NL - 1);
    int li = (l >= 1) ? ((l <= 9) ? (l - 1) : 8) : 0;   // clamped for junk lanes

    float wi0 = 0, wi1 = 0, wi2 = 0, wi3 = 0;
    float wh0, wh1, wh2, wh3;
    float bb0 = 0, bb1 = 0, bb2 = 0, bb3 = 0;
    if (isl0) {
        wh0 = sk0 * Whh0[0]; wh1 = sk1 * Whh0[1];
        wh2 = sk2 * Whh0[2]; wh3 = sk3 * Whh0[3];
    } else {
        const float* pi = Wihr + li * 4;
        const float* ph = Whhr + li * 4;
        const float* pb = br   + li * 4;
        wi0 = sk0 * pi[0]; wi1 = sk1 * pi[1]; wi2 = sk2 * pi[2]; wi3 = sk3 * pi[3];
        wh0 = sk0 * ph[0]; wh1 = sk1 * ph[1]; wh2 = sk2 * ph[2]; wh3 = sk3 * ph[3];
        bb0 = sk0 * pb[0]; bb1 = sk1 * pb[1]; bb2 = sk2 * pb[2]; bb3 = sk3 * pb[3];
    }

    const float4* G0v = (const float4*)G0 + (size_t)chain * TT;

    float h = 0.f, cs = 0.f;               // cs = -2*L2E*c
    float4 buf[DEPTH];
#pragma unroll
    for (int i = 0; i < DEPTH; i++) buf[i] = make_float4(0.f, 0.f, 0.f, 0.f);
    if (isl0) {
#pragma unroll
        for (int i = 0; i < DEPTH; i++) buf[i] = G0v[i];
    }

    for (int sb = 0; sb < 528; sb += DEPTH) {   // 33 iters x 16 steps
#pragma unroll
        for (int j = 0; j < DEPTH; j++) {
            int s = sb + j;
            int t = s - l;
            bool active = (t >= 0) && (t < TT);

            float hin = dpp_shr1(h);           // h_{l-1}(t), produced last step
            float4 g0 = buf[j];
            if (isl0 && (s + DEPTH) < TT)      // refill ring slot (static idx)
                buf[j] = G0v[s + DEPTH];

            float p0 = isl0 ? g0.x : fmaf(hin, wi0, bb0);
            float p1 = isl0 ? g0.y : fmaf(hin, wi1, bb1);
            float p2 = isl0 ? g0.z : fmaf(hin, wi2, bb2);
            float p3 = isl0 ? g0.w : fmaf(hin, wi3, bb3);
            float u0 = fmaf(h, wh0, p0);       // u = -scale*gate pre-act
            float u1 = fmaf(h, wh1, p1);
            float u2 = fmaf(h, wh2, p2);
            float u3 = fmaf(h, wh3, p3);

            float ig = frcp(1.f + fexp2(u0));                   // sigmoid(g_i)
            float fg = frcp(1.f + fexp2(u1));                   // sigmoid(g_f)
            float r2 = frcp(1.f + fexp2(u2));
            float ggs = fmaf(-4.f * L2E, r2, 2.f * L2E);        // -2L2E * tanh(g_g)
            float og = frcp(1.f + fexp2(u3));                   // sigmoid(g_o)
            float cns = fmaf(fg, cs, ig * ggs);                 // -2L2E * c_new
            float th = fmaf(2.f, frcp(1.f + fexp2(cns)), -1.f); // tanh(c_new)
            float hn = og * th;

            if (active) { cs = cns; h = hn; }
            if (isl9 && active)
                out[(size_t)chain * TT + t] = 60.f * frcp(1.f + fexp2(-L2E * hn));
        }
    }
}

// ---------------------------------------------------------------------------
// Fallback (ws too small): one thread per chain, monolithic.
// ---------------------------------------------------------------------------
__device__ __forceinline__ void cell_up(float u0, float u1, float u2, float u3,
                                        float& h, float& c)
{
    float ig = frcp(1.f + fexp2(u0));
    float fg = frcp(1.f + fexp2(u1));
    float gg = fmaf(2.f, frcp(1.f + fexp2(u2)), -1.f);
    float og = frcp(1.f + fexp2(u3));
    float cn = fmaf(fg, c, ig * gg);
    float th = fmaf(2.f, frcp(1.f + fexp2(-2.f * L2E * cn)), -1.f);
    c = cn; h = og * th;
}

__global__ __launch_bounds__(256) void k_mono(
    const float* __restrict__ x, const float* __restrict__ Wih0,
    const float* __restrict__ Whh0, const float* __restrict__ b0,
    const float* __restrict__ Wihr, const float* __restrict__ Whhr,
    const float* __restrict__ br, float* __restrict__ out)
{
    __shared__ float w[132];
    int tid = threadIdx.x;
    if (tid < 128) {
        int g = tid >> 5;
        w[tid] = ((g == 2) ? (-2.f * L2E) : (-L2E)) * Wih0[tid];
    }
    if (tid < 4) w[128 + tid] = ((tid == 2) ? (-2.f * L2E) : (-L2E)) * b0[tid];
    __syncthreads();

    int b = blockIdx.x * 256 + tid;
    float wh0[4], wir[NL - 1][4], whr[NL - 1][4], brr[NL - 1][4];
#pragma unroll
    for (int k = 0; k < 4; k++)
        wh0[k] = ((k == 2) ? (-2.f * L2E) : (-L2E)) * Whh0[k];
#pragma unroll
    for (int ll = 0; ll < NL - 1; ll++)
#pragma unroll
        for (int k = 0; k < 4; k++) {
            float s = (k == 2) ? (-2.f * L2E) : (-L2E);
            wir[ll][k] = s * Wihr[ll * 4 + k];
            whr[ll][k] = s * Whhr[ll * 4 + k];
            brr[ll][k] = s * br[ll * 4 + k];
        }
    float hh[NL], cc[NL];
#pragma unroll
    for (int ll = 0; ll < NL; ll++) { hh[ll] = 0.f; cc[ll] = 0.f; }

    const float4* xb = (const float4*)(x + (size_t)b * TT * DD);
    for (int t = 0; t < TT; t++) {
        float a0 = w[128], a1 = w[129], a2 = w[130], a3 = w[131];
#pragma unroll
        for (int ch = 0; ch < 8; ch++) {
            float4 xv = xb[t * 8 + ch];
            a0 += xv.x * w[0 * 32 + ch * 4] + xv.y * w[0 * 32 + ch * 4 + 1] + xv.z * w[0 * 32 + ch * 4 + 2] + xv.w * w[0 * 32 + ch * 4 + 3];
            a1 += xv.x * w[1 * 32 + ch * 4] + xv.y * w[1 * 32 + ch * 4 + 1] + xv.z * w[1 * 32 + ch * 4 + 2] + xv.w * w[1 * 32 + ch * 4 + 3];
            a2 += xv.x * w[2 * 32 + ch * 4] + xv.y * w[2 * 32 + ch * 4 + 1] + xv.z * w[2 * 32 + ch * 4 + 2] + xv.w * w[2 * 32 + ch * 4 + 3];
            a3 += xv.x * w[3 * 32 + ch * 4] + xv.y * w[3 * 32 + ch * 4 + 1] + xv.z * w[3 * 32 + ch * 4 + 2] + xv.w * w[3 * 32 + ch * 4 + 3];
        }
        float u0 = fmaf(hh[0], wh0[0], a0);
        float u1 = fmaf(hh[0], wh0[1], a1);
        float u2 = fmaf(hh[0], wh0[2], a2);
        float u3 = fmaf(hh[0], wh0[3], a3);
        cell_up(u0, u1, u2, u3, hh[0], cc[0]);
        float hin = hh[0];
#pragma unroll
        for (int ll = 1; ll < NL; ll++) {
            float v0 = fmaf(hin, wir[ll - 1][0], fmaf(hh[ll], whr[ll - 1][0], brr[ll - 1][0]));
            float v1 = fmaf(hin, wir[ll - 1][1], fmaf(hh[ll], whr[ll - 1][1], brr[ll - 1][1]));
            float v2 = fmaf(hin, wir[ll - 1][2], fmaf(hh[ll], whr[ll - 1][2], brr[ll - 1][2]));
            float v3 = fmaf(hin, wir[ll - 1][3], fmaf(hh[ll], whr[ll - 1][3], brr[ll - 1][3]));
            cell_up(v0, v1, v2, v3, hh[ll], cc[ll]);
            hin = hh[ll];
        }
        out[(size_t)b * TT + t] = 60.f * frcp(1.f + fexp2(-L2E * hh[NL - 1]));
    }
}

extern "C" void kernel_launch(void* const* d_in, const int* in_sizes, int n_in,
                              void* d_out, int out_size, void* d_ws, size_t ws_size,
                              hipStream_t stream)
{
    const float* x    = (const float*)d_in[0];
    const float* Wih0 = (const float*)d_in[1];
    const float* Whh0 = (const float*)d_in[2];
    const float* b0   = (const float*)d_in[3];
    const float* Wihr = (const float*)d_in[4];
    const float* Whhr = (const float*)d_in[5];
    const float* br   = (const float*)d_in[6];
    float* out = (float*)d_out;

    const size_t g0_bytes = (size_t)TT * BB * 4 * sizeof(float);   // 32 MiB
    if (ws_size >= g0_bytes) {
        float* G0 = (float*)d_ws;
        k_transform<<<(BB * TT) / 256, 256, 0, stream>>>(x, Wih0, b0, G0);
        k_pipe<<<BB / 4, 64, 0, stream>>>(G0, Whh0, Wihr, Whhr, br, out);
    } else {
        k_mono<<<BB / 256, 256, 0, stream>>>(x, Wih0, Whh0, b0, Wihr, Whhr, br, out);
    }
}

// Round 3
// 189.292 us; speedup vs baseline: 1.2034x; 1.0103x over previous
//
#include <hip/hip_runtime.h>

#define BB 4096   // batch
#define TT 512    // time steps
#define DD 32     // input dim
#define NL 10     // layers
#define PH 8      // phase length (half of the double-buffered ring)

static constexpr float L2E = 1.4426950408889634f;   // log2(e)

__device__ __forceinline__ float fexp2(float x) { return __builtin_amdgcn_exp2f(x); }
__device__ __forceinline__ float frcp(float x)  { return __builtin_amdgcn_rcpf(x); }

// row_shr:1 within each 16-lane row; lane 0 of a row gets 0 (bound_ctrl).
__device__ __forceinline__ float dpp_shr1(float x) {
    int r = __builtin_amdgcn_update_dpp(0, __float_as_int(x), 0x111, 0xF, 0xF, true);
    return __int_as_float(r);
}

// ---------------------------------------------------------------------------
// Kernel A: G0[b][t][k] = scale[k] * (W_ih0[k,:] . x[b,t,:] + b0[k])
// scale = {-L2E, -L2E, -2*L2E, -L2E}. Coalesced float4 writes ([b][t] layout).
// ---------------------------------------------------------------------------
__global__ __launch_bounds__(256) void k_transform(
    const float* __restrict__ x, const float* __restrict__ Wih0,
    const float* __restrict__ b0, float* __restrict__ G0)
{
    __shared__ float w[132];
    int tid = threadIdx.x;
    if (tid < 128) w[tid] = Wih0[tid];
    if (tid < 4)   w[128 + tid] = b0[tid];
    __syncthreads();

    int n = blockIdx.x * 256 + tid;     // n = b*TT + t

    const float4* xp = (const float4*)(x + (size_t)n * DD);
    float a0 = w[128], a1 = w[129], a2 = w[130], a3 = w[131];
#pragma unroll
    for (int ch = 0; ch < 8; ch++) {
        float4 xv = xp[ch];
        const float* w0 = &w[0 * 32 + ch * 4];
        const float* w1 = &w[1 * 32 + ch * 4];
        const float* w2 = &w[2 * 32 + ch * 4];
        const float* w3 = &w[3 * 32 + ch * 4];
        a0 += xv.x * w0[0] + xv.y * w0[1] + xv.z * w0[2] + xv.w * w0[3];
        a1 += xv.x * w1[0] + xv.y * w1[1] + xv.z * w1[2] + xv.w * w1[3];
        a2 += xv.x * w2[0] + xv.y * w2[1] + xv.z * w2[2] + xv.w * w2[3];
        a3 += xv.x * w3[0] + xv.y * w3[1] + xv.z * w3[2] + xv.w * w3[3];
    }
    float4 o;
    o.x = -L2E * a0;
    o.y = -L2E * a1;
    o.z = -2.f * L2E * a2;
    o.w = -L2E * a3;
    ((float4*)G0)[n] = o;               // coalesced
}

// ---------------------------------------------------------------------------
// Kernel B: skewed pipeline, one chain per 16-lane row (4 chains/wave),
// 1024 blocks x 1 wave = 1 wave/SIMD machine-wide. Handoff h_{l-1}(t) via
// DPP row_shr:1. Cell state kept pre-scaled (cs = -2*L2E*c).
// Memory is hoisted out of the step body: double-buffered register ring
// A[8]/B[8]; one divergent refill block per 8 steps, loads fly under the
// other phase's ALU work. Only remaining per-step branch: lane-9 store.
// ---------------------------------------------------------------------------
__global__ __launch_bounds__(64) void k_pipe(
    const float* __restrict__ G0, const float* __restrict__ Whh0,
    const float* __restrict__ Wihr, const float* __restrict__ Whhr,
    const float* __restrict__ br, float* __restrict__ out)
{
    int lane = threadIdx.x & 63;
    int cidx = lane >> 4;
    int l = lane & 15;                     // 0..9 live, 10..15 junk (isolated)
    int chain = blockIdx.x * 4 + cidx;

    const float sk0 = -L2E, sk1 = -L2E, sk2 = -2.f * L2E, sk3 = -L2E;
    bool isl0 = (l == 0), isl9 = (l == NL - 1);
    int li = (l >= 1 && l <= 9) ? (l - 1) : 0;

    float wi0 = 0, wi1 = 0, wi2 = 0, wi3 = 0;
    float wh0, wh1, wh2, wh3;
    float bb0 = 0, bb1 = 0, bb2 = 0, bb3 = 0;
    if (isl0) {
        wh0 = sk0 * Whh0[0]; wh1 = sk1 * Whh0[1];
        wh2 = sk2 * Whh0[2]; wh3 = sk3 * Whh0[3];
    } else {
        const float* pi = Wihr + li * 4;
        const float* ph = Whhr + li * 4;
        const float* pb = br   + li * 4;
        wi0 = sk0 * pi[0]; wi1 = sk1 * pi[1]; wi2 = sk2 * pi[2]; wi3 = sk3 * pi[3];
        wh0 = sk0 * ph[0]; wh1 = sk1 * ph[1]; wh2 = sk2 * ph[2]; wh3 = sk3 * ph[3];
        bb0 = sk0 * pb[0]; bb1 = sk1 * pb[1]; bb2 = sk2 * pb[2]; bb3 = sk3 * pb[3];
    }

    const float4* G0v = (const float4*)G0 + (size_t)chain * TT;

    float h = 0.f, cs = 0.f;               // cs = -2*L2E*c

    auto STEP = [&](float4 g0, int s) {
        int t = s - l;
        bool active = (t >= 0) && (t < TT);

        float hin = dpp_shr1(h);           // h_{l-1}(t), produced last step
        float p0 = isl0 ? g0.x : fmaf(hin, wi0, bb0);
        float p1 = isl0 ? g0.y : fmaf(hin, wi1, bb1);
        float p2 = isl0 ? g0.z : fmaf(hin, wi2, bb2);
        float p3 = isl0 ? g0.w : fmaf(hin, wi3, bb3);
        float u0 = fmaf(h, wh0, p0);
        float u1 = fmaf(h, wh1, p1);
        float u2 = fmaf(h, wh2, p2);
        float u3 = fmaf(h, wh3, p3);

        float ig = frcp(1.f + fexp2(u0));                   // sigmoid(g_i)
        float fg = frcp(1.f + fexp2(u1));                   // sigmoid(g_f)
        float r2 = frcp(1.f + fexp2(u2));
        float ggs = fmaf(-4.f * L2E, r2, 2.f * L2E);        // -2L2E*tanh(g_g)
        float og = frcp(1.f + fexp2(u3));                   // sigmoid(g_o)
        float cns = fmaf(fg, cs, ig * ggs);                 // -2L2E*c_new
        float th = fmaf(2.f, frcp(1.f + fexp2(cns)), -1.f); // tanh(c_new)
        float hn = og * th;

        if (active) { cs = cns; h = hn; }
        if (isl9 && active)
            out[(size_t)chain * TT + t] = 60.f * frcp(1.f + fexp2(-L2E * hn));
    };

    float4 A[PH], B[PH];
#pragma unroll
    for (int i = 0; i < PH; i++) {
        A[i] = make_float4(0.f, 0.f, 0.f, 0.f);
        B[i] = make_float4(0.f, 0.f, 0.f, 0.f);
    }
    if (isl0) {
#pragma unroll
        for (int i = 0; i < PH; i++) A[i] = G0v[i];
#pragma unroll
        for (int i = 0; i < PH; i++) B[i] = G0v[PH + i];
    }

    for (int sb = 0; sb < 528; sb += 2 * PH) {   // 33 blocks x 16 steps
        // phase 1: consume A (steps sb .. sb+7), pure ALU
#pragma unroll
        for (int j = 0; j < PH; j++) STEP(A[j], sb + j);
        // refill A <- steps sb+16 .. sb+23 (clamped); flies under phase 2
        if (isl0) {
#pragma unroll
            for (int i = 0; i < PH; i++) {
                int st = sb + 2 * PH + i;
                st = st < TT ? st : TT - 1;
                A[i] = G0v[st];
            }
        }
        // phase 2: consume B (steps sb+8 .. sb+15)
#pragma unroll
        for (int j = 0; j < PH; j++) STEP(B[j], sb + PH + j);
        // refill B <- steps sb+24 .. sb+31 (clamped); flies under next phase 1
        if (isl0) {
#pragma unroll
            for (int i = 0; i < PH; i++) {
                int st = sb + 3 * PH + i;
                st = st < TT ? st : TT - 1;
                B[i] = G0v[st];
            }
        }
    }
}

// ---------------------------------------------------------------------------
// Fallback (ws too small): one thread per chain, monolithic.
// ---------------------------------------------------------------------------
__device__ __forceinline__ void cell_up(float u0, float u1, float u2, float u3,
                                        float& h, float& c)
{
    float ig = frcp(1.f + fexp2(u0));
    float fg = frcp(1.f + fexp2(u1));
    float gg = fmaf(2.f, frcp(1.f + fexp2(u2)), -1.f);
    float og = frcp(1.f + fexp2(u3));
    float cn = fmaf(fg, c, ig * gg);
    float th = fmaf(2.f, frcp(1.f + fexp2(-2.f * L2E * cn)), -1.f);
    c = cn; h = og * th;
}

__global__ __launch_bounds__(256) void k_mono(
    const float* __restrict__ x, const float* __restrict__ Wih0,
    const float* __restrict__ Whh0, const float* __restrict__ b0,
    const float* __restrict__ Wihr, const float* __restrict__ Whhr,
    const float* __restrict__ br, float* __restrict__ out)
{
    __shared__ float w[132];
    int tid = threadIdx.x;
    if (tid < 128) {
        int g = tid >> 5;
        w[tid] = ((g == 2) ? (-2.f * L2E) : (-L2E)) * Wih0[tid];
    }
    if (tid < 4) w[128 + tid] = ((tid == 2) ? (-2.f * L2E) : (-L2E)) * b0[tid];
    __syncthreads();

    int b = blockIdx.x * 256 + tid;
    float wh0[4], wir[NL - 1][4], whr[NL - 1][4], brr[NL - 1][4];
#pragma unroll
    for (int k = 0; k < 4; k++)
        wh0[k] = ((k == 2) ? (-2.f * L2E) : (-L2E)) * Whh0[k];
#pragma unroll
    for (int ll = 0; ll < NL - 1; ll++)
#pragma unroll
        for (int k = 0; k < 4; k++) {
            float s = (k == 2) ? (-2.f * L2E) : (-L2E);
            wir[ll][k] = s * Wihr[ll * 4 + k];
            whr[ll][k] = s * Whhr[ll * 4 + k];
            brr[ll][k] = s * br[ll * 4 + k];
        }
    float hh[NL], cc[NL];
#pragma unroll
    for (int ll = 0; ll < NL; ll++) { hh[ll] = 0.f; cc[ll] = 0.f; }

    const float4* xb = (const float4*)(x + (size_t)b * TT * DD);
    for (int t = 0; t < TT; t++) {
        float a0 = w[128], a1 = w[129], a2 = w[130], a3 = w[131];
#pragma unroll
        for (int ch = 0; ch < 8; ch++) {
            float4 xv = xb[t * 8 + ch];
            a0 += xv.x * w[0 * 32 + ch * 4] + xv.y * w[0 * 32 + ch * 4 + 1] + xv.z * w[0 * 32 + ch * 4 + 2] + xv.w * w[0 * 32 + ch * 4 + 3];
            a1 += xv.x * w[1 * 32 + ch * 4] + xv.y * w[1 * 32 + ch * 4 + 1] + xv.z * w[1 * 32 + ch * 4 + 2] + xv.w * w[1 * 32 + ch * 4 + 3];
            a2 += xv.x * w[2 * 32 + ch * 4] + xv.y * w[2 * 32 + ch * 4 + 1] + xv.z * w[2 * 32 + ch * 4 + 2] + xv.w * w[2 * 32 + ch * 4 + 3];
            a3 += xv.x * w[3 * 32 + ch * 4] + xv.y * w[3 * 32 + ch * 4 + 1] + xv.z * w[3 * 32 + ch * 4 + 2] + xv.w * w[3 * 32 + ch * 4 + 3];
        }
        float u0 = fmaf(hh[0], wh0[0], a0);
        float u1 = fmaf(hh[0], wh0[1], a1);
        float u2 = fmaf(hh[0], wh0[2], a2);
        float u3 = fmaf(hh[0], wh0[3], a3);
        cell_up(u0, u1, u2, u3, hh[0], cc[0]);
        float hin = hh[0];
#pragma unroll
        for (int ll = 1; ll < NL; ll++) {
            float v0 = fmaf(hin, wir[ll - 1][0], fmaf(hh[ll], whr[ll - 1][0], brr[ll - 1][0]));
            float v1 = fmaf(hin, wir[ll - 1][1], fmaf(hh[ll], whr[ll - 1][1], brr[ll - 1][1]));
            float v2 = fmaf(hin, wir[ll - 1][2], fmaf(hh[ll], whr[ll - 1][2], brr[ll - 1][2]));
            float v3 = fmaf(hin, wir[ll - 1][3], fmaf(hh[ll], whr[ll - 1][3], brr[ll - 1][3]));
            cell_up(v0, v1, v2, v3, hh[ll], cc[ll]);
            hin = hh[ll];
        }
        out[(size_t)b * TT + t] = 60.f * frcp(1.f + fexp2(-L2E * hh[NL - 1]));
    }
}

extern "C" void kernel_launch(void* const* d_in, const int* in_sizes, int n_in,
                              void* d_out, int out_size, void* d_ws, size_t ws_size,
                              hipStream_t stream)
{
    const float* x    = (const float*)d_in[0];
    const float* Wih0 = (const float*)d_in[1];
    const float* Whh0 = (const float*)d_in[2];
    const float* b0   = (const float*)d_in[3];
    const float* Wihr = (const float*)d_in[4];
    const float* Whhr = (const float*)d_in[5];
    const float* br   = (const float*)d_in[6];
    float* out = (float*)d_out;

    const size_t g0_bytes = (size_t)TT * BB * 4 * sizeof(float);   // 32 MiB
    if (ws_size >= g0_bytes) {
        float* G0 = (float*)d_ws;
        k_transform<<<(BB * TT) / 256, 256, 0, stream>>>(x, Wih0, b0, G0);
        k_pipe<<<BB / 4, 64, 0, stream>>>(G0, Whh0, Wihr, Whhr, br, out);
    } else {
        k_mono<<<BB / 256, 256, 0, stream>>>(x, Wih0, Whh0, b0, Wihr, Whhr, br, out);
    }
}

// Round 4
// 168.292 us; speedup vs baseline: 1.3536x; 1.1248x over previous
//
#include <hip/hip_runtime.h>

#define BB 4096   // batch
#define TT 512    // time steps
#define DD 32     // input dim
#define NL 10     // layers
#define PH 8      // phase length (half of the double-buffered ring)

static constexpr float L2E = 1.4426950408889634f;   // log2(e)

__device__ __forceinline__ float fexp2(float x) { return __builtin_amdgcn_exp2f(x); }
__device__ __forceinline__ float frcp(float x)  { return __builtin_amdgcn_rcpf(x); }

// row_shr:1 within each 16-lane row; row-lane 0 gets 0 (bound_ctrl).
__device__ __forceinline__ float dpp_shr1(float x) {
    int r = __builtin_amdgcn_update_dpp(0, __float_as_int(x), 0x111, 0xF, 0xF, true);
    return __int_as_float(r);
}

// ---------------------------------------------------------------------------
// Kernel A (unchanged): G0[b][t][k] = scale[k]*(W_ih0[k,:].x[b,t,:] + b0[k])
// scale = {-L2E, -L2E, -2*L2E, -L2E}. Coalesced float4 writes.
// ---------------------------------------------------------------------------
__global__ __launch_bounds__(256) void k_transform(
    const float* __restrict__ x, const float* __restrict__ Wih0,
    const float* __restrict__ b0, float* __restrict__ G0)
{
    __shared__ float w[132];
    int tid = threadIdx.x;
    if (tid < 128) w[tid] = Wih0[tid];
    if (tid < 4)   w[128 + tid] = b0[tid];
    __syncthreads();

    int n = blockIdx.x * 256 + tid;     // n = b*TT + t

    const float4* xp = (const float4*)(x + (size_t)n * DD);
    float a0 = w[128], a1 = w[129], a2 = w[130], a3 = w[131];
#pragma unroll
    for (int ch = 0; ch < 8; ch++) {
        float4 xv = xp[ch];
        const float* w0 = &w[0 * 32 + ch * 4];
        const float* w1 = &w[1 * 32 + ch * 4];
        const float* w2 = &w[2 * 32 + ch * 4];
        const float* w3 = &w[3 * 32 + ch * 4];
        a0 += xv.x * w0[0] + xv.y * w0[1] + xv.z * w0[2] + xv.w * w0[3];
        a1 += xv.x * w1[0] + xv.y * w1[1] + xv.z * w1[2] + xv.w * w1[3];
        a2 += xv.x * w2[0] + xv.y * w2[1] + xv.z * w2[2] + xv.w * w2[3];
        a3 += xv.x * w3[0] + xv.y * w3[1] + xv.z * w3[2] + xv.w * w3[3];
    }
    float4 o;
    o.x = -L2E * a0;
    o.y = -L2E * a1;
    o.z = -2.f * L2E * a2;
    o.w = -L2E * a3;
    ((float4*)G0)[n] = o;
}

// ---------------------------------------------------------------------------
// Kernel B: skewed pipeline, one chain per 16-lane row (4 chains/wave),
// 1024 blocks x 1 wave = 1 wave/SIMD. Handoff via DPP row_shr:1.
// v4: combined-rcp gate algebra (8 trans/step), bias preloaded into ring
// regs (branchless gate injection), lane-9 output batched to one aligned
// dwordx4 store per 4 steps, cs clamped to +-88 (NaN-safe rcp form).
// State: cs = -2*L2E*c (pre-scaled).
// ---------------------------------------------------------------------------
__global__ __launch_bounds__(64) void k_pipe(
    const float* __restrict__ G0, const float* __restrict__ Whh0,
    const float* __restrict__ Wihr, const float* __restrict__ Whhr,
    const float* __restrict__ br, float* __restrict__ out)
{
    int lane = threadIdx.x & 63;
    int cidx = lane >> 4;
    int l = lane & 15;                     // 0..9 live, 10..15 junk (contained)
    int chain = blockIdx.x * 4 + cidx;

    const float sk0 = -L2E, sk1 = -L2E, sk2 = -2.f * L2E, sk3 = -L2E;
    bool isl0 = (l == 0), isl9 = (l == NL - 1);
    int li = (l >= 1 && l <= 9) ? (l - 1) : 0;

    float wi0 = 0, wi1 = 0, wi2 = 0, wi3 = 0;
    float wh0, wh1, wh2, wh3;
    float bb0 = 0, bb1 = 0, bb2 = 0, bb3 = 0;
    if (isl0) {
        wh0 = sk0 * Whh0[0]; wh1 = sk1 * Whh0[1];
        wh2 = sk2 * Whh0[2]; wh3 = sk3 * Whh0[3];
    } else {
        const float* pi = Wihr + li * 4;
        const float* ph = Whhr + li * 4;
        const float* pb = br   + li * 4;
        wi0 = sk0 * pi[0]; wi1 = sk1 * pi[1]; wi2 = sk2 * pi[2]; wi3 = sk3 * pi[3];
        wh0 = sk0 * ph[0]; wh1 = sk1 * ph[1]; wh2 = sk2 * ph[2]; wh3 = sk3 * ph[3];
        bb0 = sk0 * pb[0]; bb1 = sk1 * pb[1]; bb2 = sk2 * pb[2]; bb3 = sk3 * pb[3];
    }

    const float4* G0v = (const float4*)G0 + (size_t)chain * TT;
    float* outp = out + (size_t)chain * TT;

    const float c2  = 2.f * L2E;          // for num2 = fma(E2, c2, -c2)
    float h = 0.f, cs = 0.f;              // cs = -2*L2E*c
    float o0 = 0.f, o1 = 0.f, o2 = 0.f, o3 = 0.f;   // lane-9 output slots

    // g(step) for non-l0 lanes is the (constant) bias vector; for l0 it is
    // the precomputed input transform. Refills only touch isl0 lanes.
    float4 bbv = make_float4(bb0, bb1, bb2, bb3);
    float4 A[PH], B[PH];
#pragma unroll
    for (int i = 0; i < PH; i++) { A[i] = bbv; B[i] = bbv; }
    if (isl0) {
#pragma unroll
        for (int i = 0; i < PH; i++) A[i] = G0v[i];
#pragma unroll
        for (int i = 0; i < PH; i++) B[i] = G0v[PH + i];
    }

    auto STEP = [&](float4 g, int s, int jm) {
        int t = s - l;
        bool active = (t >= 0) && (t < TT);

        float hin = dpp_shr1(h);                      // h_{l-1}(t)
        float u0 = fmaf(h, wh0, fmaf(hin, wi0, g.x));
        float u1 = fmaf(h, wh1, fmaf(hin, wi1, g.y));
        float u2 = fmaf(h, wh2, fmaf(hin, wi2, g.z));
        float u3 = fmaf(h, wh3, fmaf(hin, wi3, g.w));

        float E0 = fexp2(u0), E1 = fexp2(u1), E2 = fexp2(u2), E3 = fexp2(u3);
        float A0 = 1.f + E0, A1 = 1.f + E1, A2 = 1.f + E2, A3 = 1.f + E3;
        // i*(-2L2E)*tanh(g_g) = (E2-1)*2L2E / (A0*A2)
        float q02  = frcp(A0 * A2);
        float num2 = fmaf(E2, c2, -c2);
        float term = num2 * q02;
        float r1   = frcp(A1);
        float csn  = fmaf(cs, r1, term);              // -2L2E*c_new
        csn = fminf(fmaxf(csn, -88.f), 88.f);         // saturate (NaN-safe)
        // h_new = o * tanh(c_new) = (1-Ec) / ((1+Ec)*A3)
        float Ec  = fexp2(csn);
        float Ac  = 1.f + Ec;
        float qc3 = frcp(Ac * A3);
        float hn  = (1.f - Ec) * qc3;

        if (active) { cs = csn; h = hn; }

        // lane-9 output collection: slot (t&3) == (jm+3)&3 (static).
        if (jm == 1) o0 = hn;
        else if (jm == 2) o1 = hn;
        else if (jm == 3) o2 = hn;
        else o3 = hn;                                  // jm == 0
        if (jm == 0 && s >= 12 && s <= 520 && isl9) {
            float4 v;
            v.x = 60.f * frcp(1.f + fexp2(-L2E * o0));
            v.y = 60.f * frcp(1.f + fexp2(-L2E * o1));
            v.z = 60.f * frcp(1.f + fexp2(-L2E * o2));
            v.w = 60.f * frcp(1.f + fexp2(-L2E * o3));
            *(float4*)(outp + (s - 12)) = v;
        }
    };

    for (int sb = 0; sb < 528; sb += 2 * PH) {   // 33 blocks x 16 steps
#pragma unroll
        for (int j = 0; j < PH; j++) STEP(A[j], sb + j, j & 3);
        if (isl0) {
#pragma unroll
            for (int i = 0; i < PH; i++) {
                int st = sb + 2 * PH + i;
                st = st < TT ? st : TT - 1;
                A[i] = G0v[st];
            }
        }
#pragma unroll
        for (int j = 0; j < PH; j++) STEP(B[j], sb + PH + j, j & 3);
        if (isl0) {
#pragma unroll
            for (int i = 0; i < PH; i++) {
                int st = sb + 3 * PH + i;
                st = st < TT ? st : TT - 1;
                B[i] = G0v[st];
            }
        }
    }
}

// ---------------------------------------------------------------------------
// Fallback (ws too small): one thread per chain, monolithic.
// ---------------------------------------------------------------------------
__device__ __forceinline__ void cell_up(float u0, float u1, float u2, float u3,
                                        float& h, float& c)
{
    float ig = frcp(1.f + fexp2(u0));
    float fg = frcp(1.f + fexp2(u1));
    float gg = fmaf(2.f, frcp(1.f + fexp2(u2)), -1.f);
    float og = frcp(1.f + fexp2(u3));
    float cn = fmaf(fg, c, ig * gg);
    float th = fmaf(2.f, frcp(1.f + fexp2(-2.f * L2E * cn)), -1.f);
    c = cn; h = og * th;
}

__global__ __launch_bounds__(256) void k_mono(
    const float* __restrict__ x, const float* __restrict__ Wih0,
    const float* __restrict__ Whh0, const float* __restrict__ b0,
    const float* __restrict__ Wihr, const float* __restrict__ Whhr,
    const float* __restrict__ br, float* __restrict__ out)
{
    __shared__ float w[132];
    int tid = threadIdx.x;
    if (tid < 128) {
        int g = tid >> 5;
        w[tid] = ((g == 2) ? (-2.f * L2E) : (-L2E)) * Wih0[tid];
    }
    if (tid < 4) w[128 + tid] = ((tid == 2) ? (-2.f * L2E) : (-L2E)) * b0[tid];
    __syncthreads();

    int b = blockIdx.x * 256 + tid;
    float wh0[4], wir[NL - 1][4], whr[NL - 1][4], brr[NL - 1][4];
#pragma unroll
    for (int k = 0; k < 4; k++)
        wh0[k] = ((k == 2) ? (-2.f * L2E) : (-L2E)) * Whh0[k];
#pragma unroll
    for (int ll = 0; ll < NL - 1; ll++)
#pragma unroll
        for (int k = 0; k < 4; k++) {
            float s = (k == 2) ? (-2.f * L2E) : (-L2E);
            wir[ll][k] = s * Wihr[ll * 4 + k];
            whr[ll][k] = s * Whhr[ll * 4 + k];
            brr[ll][k] = s * br[ll * 4 + k];
        }
    float hh[NL], cc[NL];
#pragma unroll
    for (int ll = 0; ll < NL; ll++) { hh[ll] = 0.f; cc[ll] = 0.f; }

    const float4* xb = (const float4*)(x + (size_t)b * TT * DD);
    for (int t = 0; t < TT; t++) {
        float a0 = w[128], a1 = w[129], a2 = w[130], a3 = w[131];
#pragma unroll
        for (int ch = 0; ch < 8; ch++) {
            float4 xv = xb[t * 8 + ch];
            a0 += xv.x * w[0 * 32 + ch * 4] + xv.y * w[0 * 32 + ch * 4 + 1] + xv.z * w[0 * 32 + ch * 4 + 2] + xv.w * w[0 * 32 + ch * 4 + 3];
            a1 += xv.x * w[1 * 32 + ch * 4] + xv.y * w[1 * 32 + ch * 4 + 1] + xv.z * w[1 * 32 + ch * 4 + 2] + xv.w * w[1 * 32 + ch * 4 + 3];
            a2 += xv.x * w[2 * 32 + ch * 4] + xv.y * w[2 * 32 + ch * 4 + 1] + xv.z * w[2 * 32 + ch * 4 + 2] + xv.w * w[2 * 32 + ch * 4 + 3];
            a3 += xv.x * w[3 * 32 + ch * 4] + xv.y * w[3 * 32 + ch * 4 + 1] + xv.z * w[3 * 32 + ch * 4 + 2] + xv.w * w[3 * 32 + ch * 4 + 3];
        }
        float u0 = fmaf(hh[0], wh0[0], a0);
        float u1 = fmaf(hh[0], wh0[1], a1);
        float u2 = fmaf(hh[0], wh0[2], a2);
        float u3 = fmaf(hh[0], wh0[3], a3);
        cell_up(u0, u1, u2, u3, hh[0], cc[0]);
        float hin = hh[0];
#pragma unroll
        for (int ll = 1; ll < NL; ll++) {
            float v0 = fmaf(hin, wir[ll - 1][0], fmaf(hh[ll], whr[ll - 1][0], brr[ll - 1][0]));
            float v1 = fmaf(hin, wir[ll - 1][1], fmaf(hh[ll], whr[ll - 1][1], brr[ll - 1][1]));
            float v2 = fmaf(hin, wir[ll - 1][2], fmaf(hh[ll], whr[ll - 1][2], brr[ll - 1][2]));
            float v3 = fmaf(hin, wir[ll - 1][3], fmaf(hh[ll], whr[ll - 1][3], brr[ll - 1][3]));
            cell_up(v0, v1, v2, v3, hh[ll], cc[ll]);
            hin = hh[ll];
        }
        out[(size_t)b * TT + t] = 60.f * frcp(1.f + fexp2(-L2E * hh[NL - 1]));
    }
}

extern "C" void kernel_launch(void* const* d_in, const int* in_sizes, int n_in,
                              void* d_out, int out_size, void* d_ws, size_t ws_size,
                              hipStream_t stream)
{
    const float* x    = (const float*)d_in[0];
    const float* Wih0 = (const float*)d_in[1];
    const float* Whh0 = (const float*)d_in[2];
    const float* b0   = (const float*)d_in[3];
    const float* Wihr = (const float*)d_in[4];
    const float* Whhr = (const float*)d_in[5];
    const float* br   = (const float*)d_in[6];
    float* out = (float*)d_out;

    const size_t g0_bytes = (size_t)TT * BB * 4 * sizeof(float);   // 32 MiB
    if (ws_size >= g0_bytes) {
        float* G0 = (float*)d_ws;
        k_transform<<<(BB * TT) / 256, 256, 0, stream>>>(x, Wih0, b0, G0);
        k_pipe<<<BB / 4, 64, 0, stream>>>(G0, Whh0, Wihr, Whhr, br, out);
    } else {
        k_mono<<<BB / 256, 256, 0, stream>>>(x, Wih0, Whh0, b0, Wihr, Whhr, br, out);
    }
}